// Round 8
// baseline (318.403 us; speedup 1.0000x reference)
//
#include <hip/hip_runtime.h>

typedef float f32x4 __attribute__((ext_vector_type(4)));
typedef float f32x2 __attribute__((ext_vector_type(2)));
typedef short bf16x8 __attribute__((ext_vector_type(8)));
typedef short s16x4 __attribute__((ext_vector_type(4)));

#define N_TOT 8192
#define L_OBS 20
#define P_PRED 30
#define E_DIM 64
#define H_DIM 128
#define C_DIM 2048
#define G_DIM 512
#define M_ROWS 16
#define NTH 512
#define A_PAD 200   // bf16 elems per A row (400 B rows, 16B aligned)

#define K1 1.442695041f
#define K2 2.885390082f

static __device__ __forceinline__ unsigned short f2bf(float f) {
  union { float f; unsigned int u; } v; v.f = f;
  unsigned int u = v.u;
  return (unsigned short)((u + 0x7FFFu + ((u >> 16) & 1u)) >> 16);
}
static __device__ __forceinline__ float bf2f(unsigned short b) {
  union { unsigned int u; float f; } v; v.u = ((unsigned int)b) << 16;
  return v.f;
}
// native transcendentals: avoid IEEE f32 div sequence without -ffast-math
static __device__ __forceinline__ float ex2(float x)  { float r; asm("v_exp_f32 %0, %1" : "=v"(r) : "v"(x)); return r; }
static __device__ __forceinline__ float rcpn(float x) { float r; asm("v_rcp_f32 %0, %1" : "=v"(r) : "v"(x)); return r; }
// HW round-to-nearest-even f32 pair -> packed bf16
static __device__ __forceinline__ unsigned int cvtpk(float lo, float hi) {
  unsigned int r; asm("v_cvt_pk_bf16_f32 %0, %1, %2" : "=v"(r) : "v"(lo), "v"(hi)); return r;
}

__global__ __launch_bounds__(NTH, 4)   // cap unified VGPR at 128 -> 2 WGs/CU
void lstm_traj(const float* __restrict__ img,      // [N][C]
               const float* __restrict__ obs_pos,  // [N][L][2]
               const float* __restrict__ obs_rel,  // [N][L][2]
               const int*   __restrict__ hist,     // [N]
               const float* __restrict__ h0,       // [H]
               const float* __restrict__ W_embed,  // [2][E]
               const float* __restrict__ b_embed,  // [E]
               const float* __restrict__ W_ih,     // [E][4H]
               const float* __restrict__ W_hh,     // [H][4H]
               const float* __restrict__ b_ih,     // [4H]
               const float* __restrict__ b_hh,     // [4H]
               const float* __restrict__ W_pred,   // [H+C][2]
               const float* __restrict__ b_pred,   // [2]
               float* __restrict__ out)            // [N][P][2]
{
  __shared__ unsigned short A_lds[2][M_ROWS][A_PAD]; // [e(64) | h(128) | pad]
  __shared__ float We_lds[2][E_DIM];
  __shared__ float be_lds[E_DIM];
  __shared__ float Wp_lds[H_DIM][2];

  const int t    = threadIdx.x;
  const int w    = t >> 6;        // wave 0..7
  const int l    = t & 63;
  const int u15  = l & 15;        // MFMA A-row / D-col index
  const int rq   = l >> 4;        // MFMA k-group / row-quad
  const int u    = w * 16 + u15;  // owned hidden unit 0..127
  const int wg0  = blockIdx.x * M_ROWS;
  const int grow = t >> 5;        // 0..15: row for e/rel/img work
  const int c2   = t & 31;        // 0..31: slot within row group

  const float* relrow = obs_rel + (wg0 + grow) * (L_OBS * 2);

  // ---- stage small weights to LDS ----
  if (t < 128) We_lds[t >> 6][t & 63] = W_embed[t];
  if (t < 64)  be_lds[t] = b_embed[t];
  if (t >= 128 && t < 384) ((float*)Wp_lds)[t - 128] = W_pred[t - 128];
  __syncthreads();

  // ---- B fragments (gate weights) in registers: 24 frags = 96 VGPR ----
  bf16x8 B[4][6];
#pragma unroll
  for (int ks = 0; ks < 6; ++ks)
#pragma unroll
    for (int i = 0; i < 8; ++i) {
      const int k = ks * 32 + rq * 8 + i;
      const float* Wrow = (k < E_DIM) ? (W_ih + k * G_DIM) : (W_hh + (k - E_DIM) * G_DIM);
#pragma unroll
      for (int gt = 0; gt < 4; ++gt)
        B[gt][ks][i] = (short)f2bf(Wrow[gt * 128 + u]);
    }

  // log2e-scaled negative biases
  const float nbi = -K1 * (b_ih[u]       + b_hh[u]);
  const float nbf = -K1 * (b_ih[128 + u] + b_hh[128 + u]);
  const float nbg = -K2 * (b_ih[256 + u] + b_hh[256 + u]);
  const float nbo = -K1 * (b_ih[384 + u] + b_hh[384 + u]);

  // ---- per-lane recurrent state: rows rq*4+q, unit u ----
  const float h0u = h0[u];
  const unsigned short h0b = f2bf(h0u);
  float hf[4];
  float cs[4];
  int sact = 0;   // per-q packed first-active-step (20 - hist)
#pragma unroll
  for (int q = 0; q < 4; ++q) {
    const int row = rq * 4 + q;
    hf[q] = h0u; cs[q] = h0u;
    sact |= ((20 - hist[wg0 + row]) & 255) << (8 * q);
    A_lds[0][row][64 + u] = h0b;
  }

  // wave/WG-uniform first active step (all rows inactive before it)
  int mn = 20;
#pragma unroll
  for (int q = 0; q < 4; ++q) { const int sa = (sact >> (8 * q)) & 255; mn = sa < mn ? sa : mn; }
  { int o = __shfl_xor(mn, 16); mn = o < mn ? o : mn; }
  { int o = __shfl_xor(mn, 32); mn = o < mn ? o : mn; }
  const int s_min = __builtin_amdgcn_readfirstlane(mn < 1 ? 1 : mn);

  // ---- e for first active obs step (uses obs_rel[:, s_min+1, :]) ----
  if (s_min <= L_OBS - 2) {
    const f32x2 rr = *(const f32x2*)(relrow + (s_min + 1) * 2);
    const int j = c2 * 2;
    const float e0 = fmaxf(fmaf(rr.x, We_lds[0][j],     fmaf(rr.y, We_lds[1][j],     be_lds[j])),     0.f);
    const float e1 = fmaxf(fmaf(rr.x, We_lds[0][j + 1], fmaf(rr.y, We_lds[1][j + 1], be_lds[j + 1])), 0.f);
    *(unsigned int*)&A_lds[0][grow][j] = cvtpk(e0, e1);
  }

  // ---- pos init + img_proj (32 lanes per row, coalesced float4) ----
  float pos0 = obs_pos[(wg0 + grow) * (L_OBS * 2) + (L_OBS - 1) * 2];
  float pos1 = obs_pos[(wg0 + grow) * (L_OBS * 2) + (L_OBS - 1) * 2 + 1];
  float ip0 = 0.f, ip1 = 0.f;
  {
    const float* irow = img + (long)(wg0 + grow) * C_DIM;
#pragma unroll 4
    for (int i = 0; i < 16; ++i) {
      const int k0 = i * 128 + c2 * 4;
      const f32x4 v  = *(const f32x4*)(irow + k0);
      const f32x4 wa = *(const f32x4*)(W_pred + (H_DIM + k0) * 2);
      const f32x4 wb = *(const f32x4*)(W_pred + (H_DIM + k0) * 2 + 4);
      ip0 = fmaf(v.x, wa.x, fmaf(v.y, wa.z, fmaf(v.z, wb.x, fmaf(v.w, wb.z, ip0))));
      ip1 = fmaf(v.x, wa.y, fmaf(v.y, wa.w, fmaf(v.z, wb.y, fmaf(v.w, wb.w, ip1))));
    }
#pragma unroll
    for (int m = 16; m >= 1; m >>= 1) { ip0 += __shfl_xor(ip0, m); ip1 += __shfl_xor(ip1, m); }
    ip0 += b_pred[0]; ip1 += b_pred[1];
  }
  __syncthreads();  // A_lds[0] ready

  int cur = 0;

  // gate nonlinearity + h-write: 5 ex2 + 2 rcp per output
  auto gates_and_h = [&](f32x4 (&a4)[4], int nxt_, int s_, bool domask) {
#pragma unroll
    for (int q = 0; q < 4; ++q) {
      const float A_ = ex2(fmaf(a4[0][q], -K1, nbi));
      const float F_ = ex2(fmaf(a4[1][q], -K1, nbf));
      const float B_ = ex2(fmaf(a4[2][q], -K2, nbg));
      const float C_ = ex2(fmaf(a4[3][q], -K1, nbo));
      const float P2 = 1.f + B_;
      const float PB = (1.f + A_) * P2;
      const float Q  = 1.f + F_;
      const float cn = fmaf(cs[q], PB, (2.f - P2) * Q) * rcpn(PB * Q);
      const float cc = fmaxf(fminf(cn, 40.f), -40.f);
      const float D_ = ex2(-K2 * cc);
      const float hn = (1.f - D_) * rcpn((1.f + D_) * (1.f + C_)); // tanh(cn)*sigmoid(o)
      bool act = true;
      if (domask) act = s_ >= ((sact >> (8 * q)) & 255);
      if (act) { cs[q] = cn; hf[q] = hn; }
    }
    const unsigned int p01 = cvtpk(hf[0], hf[1]);
    const unsigned int p23 = cvtpk(hf[2], hf[3]);
    const int rowb = rq * 4;
    A_lds[nxt_][rowb + 0][64 + u] = (unsigned short)p01;
    A_lds[nxt_][rowb + 1][64 + u] = (unsigned short)(p01 >> 16);
    A_lds[nxt_][rowb + 2][64 + u] = (unsigned short)p23;
    A_lds[nxt_][rowb + 3][64 + u] = (unsigned short)(p23 >> 16);
  };

  // ================= obs phase: steps s_min..18 =================
#pragma unroll 1
  for (int s = s_min; s < L_OBS - 1; ++s) {
    const int nxt = cur ^ 1;
    const int sN = (s + 2 <= L_OBS - 1) ? (s + 2) : (L_OBS - 1);  // branchless prefetch idx
    const f32x2 rrN = *(const f32x2*)(relrow + sN * 2);

    f32x4 acc[4];
#pragma unroll
    for (int gt = 0; gt < 4; ++gt) { acc[gt].x = 0.f; acc[gt].y = 0.f; acc[gt].z = 0.f; acc[gt].w = 0.f; }
#pragma unroll
    for (int ks = 0; ks < 6; ++ks) {
      const bf16x8 a = *(const bf16x8*)&A_lds[cur][u15][ks * 32 + rq * 8];
#pragma unroll
      for (int gt = 0; gt < 4; ++gt)
        acc[gt] = __builtin_amdgcn_mfma_f32_16x16x32_bf16(a, B[gt][ks], acc[gt], 0, 0, 0);
    }

    // next-step e into A[nxt] (fills MFMA shadow; garbage on last iter, overwritten in pred)
    {
      const int j = c2 * 2;
      const float e0 = fmaxf(fmaf(rrN.x, We_lds[0][j],     fmaf(rrN.y, We_lds[1][j],     be_lds[j])),     0.f);
      const float e1 = fmaxf(fmaf(rrN.x, We_lds[0][j + 1], fmaf(rrN.y, We_lds[1][j + 1], be_lds[j + 1])), 0.f);
      *(unsigned int*)&A_lds[nxt][grow][j] = cvtpk(e0, e1);
    }

    gates_and_h(acc, nxt, s, true);
    cur = nxt;
    __syncthreads();
  }

  // ================= pred phase: 30 steps (two barriers, r4 structure) =================
#pragma unroll 1
  for (int p = 0; p < P_PRED; ++p) {
    const bool last = (p == P_PRED - 1);

    // serial rel chain started early: hv read + per-lane dot (4 units)
    const s16x4 hv = *(const s16x4*)&A_lds[cur][grow][64 + c2 * 4];
    float s0 = 0.f, s1 = 0.f;
#pragma unroll
    for (int i = 0; i < 4; ++i) {
      const float hfv = bf2f((unsigned short)hv[i]);
      s0 = fmaf(hfv, Wp_lds[c2 * 4 + i][0], s0);
      s1 = fmaf(hfv, Wp_lds[c2 * 4 + i][1], s1);
    }

    // h-part MFMAs (ks 2..5); overlap the shuffle tree
    f32x4 acc[4];
    if (!last) {
#pragma unroll
      for (int gt = 0; gt < 4; ++gt) { acc[gt].x = 0.f; acc[gt].y = 0.f; acc[gt].z = 0.f; acc[gt].w = 0.f; }
#pragma unroll
      for (int ks4 = 0; ks4 < 4; ++ks4) {
        const bf16x8 a = *(const bf16x8*)&A_lds[cur][u15][64 + ks4 * 32 + rq * 8];
#pragma unroll
        for (int gt = 0; gt < 4; ++gt)
          acc[gt] = __builtin_amdgcn_mfma_f32_16x16x32_bf16(a, B[gt][ks4 + 2], acc[gt], 0, 0, 0);
      }
    }

    // finish rel reduction (within 32-lane row group)
#pragma unroll
    for (int m = 16; m >= 1; m >>= 1) { s0 += __shfl_xor(s0, m); s1 += __shfl_xor(s1, m); }
    const float rel0 = s0 + ip0, rel1 = s1 + ip1;
    pos0 += rel0; pos1 += rel1;
    if (c2 == 0) {
      float2 o; o.x = pos0; o.y = pos1;
      *(float2*)&out[((long)(wg0 + grow) * P_PRED + p) * 2] = o;
    }
    if (last) break;

    // e = relu(rel @ W_embed + b_embed) into A[cur] cols 0..63 (disjoint from h reads)
    {
      const int j = c2 * 2;
      const float e0 = fmaxf(fmaf(rel0, We_lds[0][j],     fmaf(rel1, We_lds[1][j],     be_lds[j])),     0.f);
      const float e1 = fmaxf(fmaf(rel0, We_lds[0][j + 1], fmaf(rel1, We_lds[1][j + 1], be_lds[j + 1])), 0.f);
      *(unsigned int*)&A_lds[cur][grow][j] = cvtpk(e0, e1);
    }
    __syncthreads();  // barrier B: e visible

    // e-part MFMAs (ks 0..1)
#pragma unroll
    for (int ks = 0; ks < 2; ++ks) {
      const bf16x8 a = *(const bf16x8*)&A_lds[cur][u15][ks * 32 + rq * 8];
#pragma unroll
      for (int gt = 0; gt < 4; ++gt)
        acc[gt] = __builtin_amdgcn_mfma_f32_16x16x32_bf16(a, B[gt][ks], acc[gt], 0, 0, 0);
    }

    const int nxt = cur ^ 1;
    gates_and_h(acc, nxt, 0, false);
    cur = nxt;
    __syncthreads();  // barrier A: h visible
  }
}

extern "C" void kernel_launch(void* const* d_in, const int* in_sizes, int n_in,
                              void* d_out, int out_size, void* d_ws, size_t ws_size,
                              hipStream_t stream) {
  (void)in_sizes; (void)n_in; (void)out_size; (void)d_ws; (void)ws_size;
  lstm_traj<<<dim3(N_TOT / M_ROWS), dim3(NTH), 0, stream>>>(
      (const float*)d_in[0],  // img_embedding
      (const float*)d_in[1],  // obs_pos
      (const float*)d_in[2],  // obs_pos_rel
      (const int*)  d_in[3],  // obs_hist_size
      (const float*)d_in[4],  // h0
      (const float*)d_in[5],  // W_embed
      (const float*)d_in[6],  // b_embed
      (const float*)d_in[7],  // W_ih
      (const float*)d_in[8],  // W_hh
      (const float*)d_in[9],  // b_ih
      (const float*)d_in[10], // b_hh
      (const float*)d_in[11], // W_pred
      (const float*)d_in[12], // b_pred
      (float*)d_out);
}

// Round 9
// 155.076 us; speedup vs baseline: 2.0532x; 2.0532x over previous
//
#include <hip/hip_runtime.h>

typedef float f32x4 __attribute__((ext_vector_type(4)));
typedef float f32x2 __attribute__((ext_vector_type(2)));
typedef short bf16x8 __attribute__((ext_vector_type(8)));
typedef short s16x4 __attribute__((ext_vector_type(4)));

#define N_TOT 8192
#define L_OBS 20
#define P_PRED 30
#define E_DIM 64
#define H_DIM 128
#define C_DIM 2048
#define G_DIM 512
#define M_ROWS 32
#define NTH 1024
#define A_PAD 200   // bf16 elems per A row (400 B rows, 16B aligned)

#define K1 1.442695041f
#define K2 2.885390082f

static __device__ __forceinline__ unsigned short f2bf(float f) {
  union { float f; unsigned int u; } v; v.f = f;
  unsigned int u = v.u;
  return (unsigned short)((u + 0x7FFFu + ((u >> 16) & 1u)) >> 16);
}
static __device__ __forceinline__ float bf2f(unsigned short b) {
  union { unsigned int u; float f; } v; v.u = ((unsigned int)b) << 16;
  return v.f;
}
static __device__ __forceinline__ float ex2(float x)  { float r; asm("v_exp_f32 %0, %1" : "=v"(r) : "v"(x)); return r; }
static __device__ __forceinline__ float rcpn(float x) { float r; asm("v_rcp_f32 %0, %1" : "=v"(r) : "v"(x)); return r; }
static __device__ __forceinline__ unsigned int cvtpk(float lo, float hi) {
  unsigned int r; asm("v_cvt_pk_bf16_f32 %0, %1, %2" : "=v"(r) : "v"(lo), "v"(hi)); return r;
}

// 1024-thread block: 16 waves forced co-resident (4/SIMD) -> compiler caps VGPR at 128.
__global__ __launch_bounds__(NTH, 1)
void lstm_traj(const float* __restrict__ img,      // [N][C]
               const float* __restrict__ obs_pos,  // [N][L][2]
               const float* __restrict__ obs_rel,  // [N][L][2]
               const int*   __restrict__ hist,     // [N]
               const float* __restrict__ h0,       // [H]
               const float* __restrict__ W_embed,  // [2][E]
               const float* __restrict__ b_embed,  // [E]
               const float* __restrict__ W_ih,     // [E][4H]
               const float* __restrict__ W_hh,     // [H][4H]
               const float* __restrict__ b_ih,     // [4H]
               const float* __restrict__ b_hh,     // [4H]
               const float* __restrict__ W_pred,   // [H+C][2]
               const float* __restrict__ b_pred,   // [2]
               float* __restrict__ out)            // [N][P][2]
{
  __shared__ unsigned short A_lds[2][M_ROWS][A_PAD]; // [e(64) | h(128) | pad]
  __shared__ float We_lds[2][E_DIM];
  __shared__ float be_lds[E_DIM];
  __shared__ float Wp_lds[H_DIM][2];

  const int t    = threadIdx.x;
  const int w    = t >> 6;        // wave 0..15: owns units w*8..w*8+7 (x 4 gates = 32 cols)
  const int l    = t & 63;
  const int u15  = l & 15;        // MFMA A-row / D-col index
  const int rq   = l >> 4;        // MFMA k-group / row-quad
  const int hi   = u15 >> 3;      // 0: lane holds gates i,g ; 1: gates f,o  (also rt-half for gates)
  const int myu  = w * 8 + (u15 & 7);  // owned hidden unit
  const int wg0  = blockIdx.x * M_ROWS;
  const int grow = t >> 5;        // 0..31: row for e/rel/img work
  const int c2   = t & 31;        // 0..31: slot within row group

  const float* relrow = obs_rel + (wg0 + grow) * (L_OBS * 2);

  // ---- stage small weights to LDS ----
  if (t < 128) We_lds[t >> 6][t & 63] = W_embed[t];
  if (t < 64)  be_lds[t] = b_embed[t];
  if (t >= 128 && t < 384) ((float*)Wp_lds)[t - 128] = W_pred[t - 128];
  __syncthreads();

  // ---- B fragments: virtual col layout within tile T: gate = T*2+(c>>3), unit = w*8+(c&7)
  // lane u15 -> col u15: gate gT = T*2 + hi, unit myu.  12 frags = 48 VGPR.
  bf16x8 B[2][6];
#pragma unroll
  for (int T = 0; T < 2; ++T) {
    const int gcol = (T * 2 + hi) * 128 + myu;
#pragma unroll
    for (int ks = 0; ks < 6; ++ks)
#pragma unroll
      for (int i = 0; i < 8; ++i) {
        const int k = ks * 32 + rq * 8 + i;
        const float* Wrow = (k < E_DIM) ? (W_ih + k * G_DIM) : (W_hh + (k - E_DIM) * G_DIM);
        B[T][ks][i] = (short)f2bf(Wrow[gcol]);
      }
  }

  // ---- bias seeds (unscaled; scale folded at ex2) ----
  f32x4 bseed[2];
#pragma unroll
  for (int T = 0; T < 2; ++T) {
    const int gcol = (T * 2 + hi) * 128 + myu;
    const float b = b_ih[gcol] + b_hh[gcol];
    bseed[T].x = b; bseed[T].y = b; bseed[T].z = b; bseed[T].w = b;
  }

  // ---- per-lane state: unit myu, rows hi*16 + rq*4 + q ----
  const float h0u = h0[myu];
  const unsigned short h0b = f2bf(h0u);
  float cs[4], hreg[4];
  int sact = 0;
#pragma unroll
  for (int q = 0; q < 4; ++q) {
    const int row = hi * 16 + rq * 4 + q;
    cs[q] = h0u; hreg[q] = h0u;
    sact |= ((20 - hist[wg0 + row]) & 255) << (8 * q);
    A_lds[0][row][64 + myu] = h0b;
  }

  // WG-uniform first-active step: every wave sees all 32 rows (rows depend on hi,rq,q only)
  int mn = 20;
#pragma unroll
  for (int q = 0; q < 4; ++q) { const int sa = (sact >> (8 * q)) & 255; mn = sa < mn ? sa : mn; }
  { int o = __shfl_xor(mn, 8);  mn = o < mn ? o : mn; }
  { int o = __shfl_xor(mn, 16); mn = o < mn ? o : mn; }
  { int o = __shfl_xor(mn, 32); mn = o < mn ? o : mn; }
  const int s_min = __builtin_amdgcn_readfirstlane(mn < 1 ? 1 : mn);

  // ---- e for first active obs step ----
  if (s_min <= L_OBS - 2) {
    const f32x2 rr = *(const f32x2*)(relrow + (s_min + 1) * 2);
    const int j = c2 * 2;
    const float e0 = fmaxf(fmaf(rr.x, We_lds[0][j],     fmaf(rr.y, We_lds[1][j],     be_lds[j])),     0.f);
    const float e1 = fmaxf(fmaf(rr.x, We_lds[0][j + 1], fmaf(rr.y, We_lds[1][j + 1], be_lds[j + 1])), 0.f);
    *(unsigned int*)&A_lds[0][grow][j] = cvtpk(e0, e1);
  }

  // ---- pos init + img_proj (32 lanes per row, coalesced float4) ----
  float pos0 = obs_pos[(wg0 + grow) * (L_OBS * 2) + (L_OBS - 1) * 2];
  float pos1 = obs_pos[(wg0 + grow) * (L_OBS * 2) + (L_OBS - 1) * 2 + 1];
  float ip0 = 0.f, ip1 = 0.f;
  {
    const float* irow = img + (long)(wg0 + grow) * C_DIM;
#pragma unroll 4
    for (int i = 0; i < 16; ++i) {
      const int k0 = i * 128 + c2 * 4;
      const f32x4 v  = *(const f32x4*)(irow + k0);
      const f32x4 wa = *(const f32x4*)(W_pred + (H_DIM + k0) * 2);
      const f32x4 wb = *(const f32x4*)(W_pred + (H_DIM + k0) * 2 + 4);
      ip0 = fmaf(v.x, wa.x, fmaf(v.y, wa.z, fmaf(v.z, wb.x, fmaf(v.w, wb.z, ip0))));
      ip1 = fmaf(v.x, wa.y, fmaf(v.y, wa.w, fmaf(v.z, wb.y, fmaf(v.w, wb.w, ip1))));
    }
#pragma unroll
    for (int m = 16; m >= 1; m >>= 1) { ip0 += __shfl_xor(ip0, m); ip1 += __shfl_xor(ip1, m); }
    ip0 += b_pred[0]; ip1 += b_pred[1];
  }
  __syncthreads();  // A_lds[0] ready

  int cur = 0;

  // exchange + gates + h-write. acc[rt][T] holds gate (T*2+hi) of myu, rows rt*16+rq*4+q, bias included.
  auto gates_and_h = [&](f32x4 (&acc)[2][2], int nxt_, int s_, bool domask) {
    // partner (lane ^ 8) values
    f32x4 px[2][2];
#pragma unroll
    for (int rt = 0; rt < 2; ++rt)
#pragma unroll
      for (int T = 0; T < 2; ++T)
#pragma unroll
        for (int q = 0; q < 4; ++q)
          px[rt][T][q] = __shfl_xor(acc[rt][T][q], 8);
#pragma unroll
    for (int q = 0; q < 4; ++q) {
      // lane-half hi processes rt = hi
      const float iv = hi ? px[1][0][q] : acc[0][0][q];
      const float fv = hi ? acc[1][0][q] : px[0][0][q];
      const float gv = hi ? px[1][1][q] : acc[0][1][q];
      const float ov = hi ? acc[1][1][q] : px[0][1][q];
      const float A_ = ex2(-K1 * iv);
      const float F_ = ex2(-K1 * fv);
      const float B_ = ex2(-K2 * gv);
      const float C_ = ex2(-K1 * ov);
      const float P2 = 1.f + B_;
      const float PB = (1.f + A_) * P2;
      const float Q  = 1.f + F_;
      const float cn = fmaf(cs[q], PB, (2.f - P2) * Q) * rcpn(PB * Q);
      const float cc = fmaxf(fminf(cn, 40.f), -40.f);
      const float D_ = ex2(-K2 * cc);
      const float hn = (1.f - D_) * rcpn((1.f + D_) * (1.f + C_)); // tanh(cn)*sigmoid(o)
      bool act = true;
      if (domask) act = s_ >= ((sact >> (8 * q)) & 255);
      if (act) { cs[q] = cn; hreg[q] = hn; }
    }
    const unsigned int p01 = cvtpk(hreg[0], hreg[1]);
    const unsigned int p23 = cvtpk(hreg[2], hreg[3]);
    const int rowb = hi * 16 + rq * 4;
    A_lds[nxt_][rowb + 0][64 + myu] = (unsigned short)p01;
    A_lds[nxt_][rowb + 1][64 + myu] = (unsigned short)(p01 >> 16);
    A_lds[nxt_][rowb + 2][64 + myu] = (unsigned short)p23;
    A_lds[nxt_][rowb + 3][64 + myu] = (unsigned short)(p23 >> 16);
  };

  // ================= obs phase: steps s_min..18 =================
#pragma unroll 1
  for (int s = s_min; s < L_OBS - 1; ++s) {
    const int nxt = cur ^ 1;
    const int sN = (s + 2 <= L_OBS - 1) ? (s + 2) : (L_OBS - 1);
    const f32x2 rrN = *(const f32x2*)(relrow + sN * 2);

    f32x4 acc[2][2];
#pragma unroll
    for (int rt = 0; rt < 2; ++rt) {
      {
        const bf16x8 a = *(const bf16x8*)&A_lds[cur][rt * 16 + u15][rq * 8];
#pragma unroll
        for (int T = 0; T < 2; ++T)
          acc[rt][T] = __builtin_amdgcn_mfma_f32_16x16x32_bf16(a, B[T][0], bseed[T], 0, 0, 0);
      }
#pragma unroll
      for (int ks = 1; ks < 6; ++ks) {
        const bf16x8 a = *(const bf16x8*)&A_lds[cur][rt * 16 + u15][ks * 32 + rq * 8];
#pragma unroll
        for (int T = 0; T < 2; ++T)
          acc[rt][T] = __builtin_amdgcn_mfma_f32_16x16x32_bf16(a, B[T][ks], acc[rt][T], 0, 0, 0);
      }
    }

    // next-step e into A[nxt] (fills MFMA shadow)
    {
      const int j = c2 * 2;
      const float e0 = fmaxf(fmaf(rrN.x, We_lds[0][j],     fmaf(rrN.y, We_lds[1][j],     be_lds[j])),     0.f);
      const float e1 = fmaxf(fmaf(rrN.x, We_lds[0][j + 1], fmaf(rrN.y, We_lds[1][j + 1], be_lds[j + 1])), 0.f);
      *(unsigned int*)&A_lds[nxt][grow][j] = cvtpk(e0, e1);
    }

    gates_and_h(acc, nxt, s, true);
    cur = nxt;
    __syncthreads();
  }

  // ================= pred phase: 30 steps =================
#pragma unroll 1
  for (int p = 0; p < P_PRED; ++p) {
    const bool last = (p == P_PRED - 1);

    // rel chain: hv read + per-lane partial dot (4 units)
    const s16x4 hv = *(const s16x4*)&A_lds[cur][grow][64 + c2 * 4];
    float s0 = 0.f, s1 = 0.f;
#pragma unroll
    for (int i = 0; i < 4; ++i) {
      const float hfv = bf2f((unsigned short)hv[i]);
      s0 = fmaf(hfv, Wp_lds[c2 * 4 + i][0], s0);
      s1 = fmaf(hfv, Wp_lds[c2 * 4 + i][1], s1);
    }

    // h-part MFMAs (ks 2..5), bias-seeded; overlap the shuffle tree
    f32x4 acc[2][2];
    if (!last) {
#pragma unroll
      for (int rt = 0; rt < 2; ++rt)
#pragma unroll
        for (int ks4 = 0; ks4 < 4; ++ks4) {
          const bf16x8 a = *(const bf16x8*)&A_lds[cur][rt * 16 + u15][64 + ks4 * 32 + rq * 8];
#pragma unroll
          for (int T = 0; T < 2; ++T)
            acc[rt][T] = __builtin_amdgcn_mfma_f32_16x16x32_bf16(
                a, B[T][ks4 + 2], ks4 == 0 ? bseed[T] : acc[rt][T], 0, 0, 0);
        }
    }

    // finish rel reduction (within 32-lane row group)
#pragma unroll
    for (int m = 16; m >= 1; m >>= 1) { s0 += __shfl_xor(s0, m); s1 += __shfl_xor(s1, m); }
    const float rel0 = s0 + ip0, rel1 = s1 + ip1;
    pos0 += rel0; pos1 += rel1;
    if (c2 == 0) {
      float2 o; o.x = pos0; o.y = pos1;
      *(float2*)&out[((long)(wg0 + grow) * P_PRED + p) * 2] = o;
    }
    if (last) break;

    // e = relu(rel @ W_embed + b_embed) into A[cur] cols 0..63
    {
      const int j = c2 * 2;
      const float e0 = fmaxf(fmaf(rel0, We_lds[0][j],     fmaf(rel1, We_lds[1][j],     be_lds[j])),     0.f);
      const float e1 = fmaxf(fmaf(rel0, We_lds[0][j + 1], fmaf(rel1, We_lds[1][j + 1], be_lds[j + 1])), 0.f);
      *(unsigned int*)&A_lds[cur][grow][j] = cvtpk(e0, e1);
    }
    __syncthreads();  // barrier B: e visible

    // e-part MFMAs (ks 0..1)
#pragma unroll
    for (int rt = 0; rt < 2; ++rt)
#pragma unroll
      for (int ks = 0; ks < 2; ++ks) {
        const bf16x8 a = *(const bf16x8*)&A_lds[cur][rt * 16 + u15][ks * 32 + rq * 8];
#pragma unroll
        for (int T = 0; T < 2; ++T)
          acc[rt][T] = __builtin_amdgcn_mfma_f32_16x16x32_bf16(a, B[T][ks], acc[rt][T], 0, 0, 0);
      }

    const int nxt = cur ^ 1;
    gates_and_h(acc, nxt, 0, false);
    cur = nxt;
    __syncthreads();  // barrier A: h visible
  }
}

extern "C" void kernel_launch(void* const* d_in, const int* in_sizes, int n_in,
                              void* d_out, int out_size, void* d_ws, size_t ws_size,
                              hipStream_t stream) {
  (void)in_sizes; (void)n_in; (void)out_size; (void)d_ws; (void)ws_size;
  lstm_traj<<<dim3(N_TOT / M_ROWS), dim3(NTH), 0, stream>>>(
      (const float*)d_in[0],  // img_embedding
      (const float*)d_in[1],  // obs_pos
      (const float*)d_in[2],  // obs_pos_rel
      (const int*)  d_in[3],  // obs_hist_size
      (const float*)d_in[4],  // h0
      (const float*)d_in[5],  // W_embed
      (const float*)d_in[6],  // b_embed
      (const float*)d_in[7],  // W_ih
      (const float*)d_in[8],  // W_hh
      (const float*)d_in[9],  // b_ih
      (const float*)d_in[10], // b_hh
      (const float*)d_in[11], // W_pred
      (const float*)d_in[12], // b_pred
      (float*)d_out);
}

// Round 10
// 151.945 us; speedup vs baseline: 2.0955x; 1.0206x over previous
//
#include <hip/hip_runtime.h>

typedef float f32x4 __attribute__((ext_vector_type(4)));
typedef float f32x2 __attribute__((ext_vector_type(2)));
typedef short bf16x8 __attribute__((ext_vector_type(8)));
typedef short s16x4 __attribute__((ext_vector_type(4)));

#define N_TOT 8192
#define L_OBS 20
#define P_PRED 30
#define E_DIM 64
#define H_DIM 128
#define C_DIM 2048
#define G_DIM 512
#define M_ROWS 32
#define NTH 1024
#define A_PAD 200   // bf16 elems per A row (400 B rows, 16B aligned)

#define K1 1.442695041f
#define K2 2.885390082f

static __device__ __forceinline__ unsigned short f2bf(float f) {
  union { float f; unsigned int u; } v; v.f = f;
  unsigned int u = v.u;
  return (unsigned short)((u + 0x7FFFu + ((u >> 16) & 1u)) >> 16);
}
static __device__ __forceinline__ float bf2f(unsigned short b) {
  union { unsigned int u; float f; } v; v.u = ((unsigned int)b) << 16;
  return v.f;
}
static __device__ __forceinline__ float ex2(float x)  { float r; asm("v_exp_f32 %0, %1" : "=v"(r) : "v"(x)); return r; }
static __device__ __forceinline__ float rcpn(float x) { float r; asm("v_rcp_f32 %0, %1" : "=v"(r) : "v"(x)); return r; }
static __device__ __forceinline__ unsigned int cvtpk(float lo, float hi) {
  unsigned int r; asm("v_cvt_pk_bf16_f32 %0, %1, %2" : "=v"(r) : "v"(lo), "v"(hi)); return r;
}

// 1024-thread block (16 waves, 4/SIMD). waves_per_eu(4,4) pins the register
// budget at 128/lane so the compiler cannot squeeze to 64 and spill (r9 lesson).
__global__ __launch_bounds__(NTH)
__attribute__((amdgpu_waves_per_eu(4, 4)))
void lstm_traj(const float* __restrict__ img,      // [N][C]
               const float* __restrict__ obs_pos,  // [N][L][2]
               const float* __restrict__ obs_rel,  // [N][L][2]
               const int*   __restrict__ hist,     // [N]
               const float* __restrict__ h0,       // [H]
               const float* __restrict__ W_embed,  // [2][E]
               const float* __restrict__ b_embed,  // [E]
               const float* __restrict__ W_ih,     // [E][4H]
               const float* __restrict__ W_hh,     // [H][4H]
               const float* __restrict__ b_ih,     // [4H]
               const float* __restrict__ b_hh,     // [4H]
               const float* __restrict__ W_pred,   // [H+C][2]
               const float* __restrict__ b_pred,   // [2]
               float* __restrict__ out)            // [N][P][2]
{
  __shared__ unsigned short A_lds[2][M_ROWS][A_PAD]; // [e(64) | h(128) | pad]
  __shared__ float We_lds[2][E_DIM];
  __shared__ float be_lds[E_DIM];
  __shared__ float Wp_lds[H_DIM][2];

  const int t    = threadIdx.x;
  const int w    = t >> 6;        // wave 0..15: owns units w*8..w*8+7 (x 4 gates = 32 cols)
  const int l    = t & 63;
  const int u15  = l & 15;        // MFMA A-row / D-col index
  const int rq   = l >> 4;        // MFMA k-group / row-quad
  const int hi   = u15 >> 3;      // 0: lane holds gates i,g ; 1: gates f,o ; processes rt=hi rows
  const int myu  = w * 8 + (u15 & 7);  // owned hidden unit
  const int wg0  = blockIdx.x * M_ROWS;
  const int grow = t >> 5;        // 0..31: row for e/rel/img work
  const int c2   = t & 31;        // 0..31: slot within row group

  const float* relrow = obs_rel + (wg0 + grow) * (L_OBS * 2);

  // ---- stage small weights to LDS ----
  if (t < 128) We_lds[t >> 6][t & 63] = W_embed[t];
  if (t < 64)  be_lds[t] = b_embed[t];
  if (t >= 128 && t < 384) ((float*)Wp_lds)[t - 128] = W_pred[t - 128];
  __syncthreads();

  // ---- B fragments: tile T, col c -> gate T*2+(c>>3), unit w*8+(c&7). 12 frags = 48 VGPR.
  bf16x8 B[2][6];
#pragma unroll
  for (int T = 0; T < 2; ++T) {
    const int gcol = (T * 2 + hi) * 128 + myu;
#pragma unroll
    for (int ks = 0; ks < 6; ++ks)
#pragma unroll
      for (int i = 0; i < 8; ++i) {
        const int k = ks * 32 + rq * 8 + i;
        const float* Wrow = (k < E_DIM) ? (W_ih + k * G_DIM) : (W_hh + (k - E_DIM) * G_DIM);
        B[T][ks][i] = (short)f2bf(Wrow[gcol]);
      }
  }

  // ---- log2e-scaled negative biases for ALL 4 gates of myu (4 regs) ----
  const float nbi = -K1 * (b_ih[myu]       + b_hh[myu]);
  const float nbf = -K1 * (b_ih[128 + myu] + b_hh[128 + myu]);
  const float nbg = -K2 * (b_ih[256 + myu] + b_hh[256 + myu]);
  const float nbo = -K1 * (b_ih[384 + myu] + b_hh[384 + myu]);

  // ---- per-lane state: unit myu, rows hi*16 + rq*4 + q ----
  const float h0u = h0[myu];
  const unsigned short h0b = f2bf(h0u);
  float cs[4], hreg[4];
  int sact = 0;
#pragma unroll
  for (int q = 0; q < 4; ++q) {
    const int row = hi * 16 + rq * 4 + q;
    cs[q] = h0u; hreg[q] = h0u;
    sact |= ((20 - hist[wg0 + row]) & 255) << (8 * q);
    A_lds[0][row][64 + myu] = h0b;
  }

  // WG-uniform first-active step
  int mn = 20;
#pragma unroll
  for (int q = 0; q < 4; ++q) { const int sa = (sact >> (8 * q)) & 255; mn = sa < mn ? sa : mn; }
  { int o = __shfl_xor(mn, 8);  mn = o < mn ? o : mn; }
  { int o = __shfl_xor(mn, 16); mn = o < mn ? o : mn; }
  { int o = __shfl_xor(mn, 32); mn = o < mn ? o : mn; }
  const int s_min = __builtin_amdgcn_readfirstlane(mn < 1 ? 1 : mn);

  // ---- e for first active obs step ----
  if (s_min <= L_OBS - 2) {
    const f32x2 rr = *(const f32x2*)(relrow + (s_min + 1) * 2);
    const int j = c2 * 2;
    const float e0 = fmaxf(fmaf(rr.x, We_lds[0][j],     fmaf(rr.y, We_lds[1][j],     be_lds[j])),     0.f);
    const float e1 = fmaxf(fmaf(rr.x, We_lds[0][j + 1], fmaf(rr.y, We_lds[1][j + 1], be_lds[j + 1])), 0.f);
    *(unsigned int*)&A_lds[0][grow][j] = cvtpk(e0, e1);
  }

  // ---- pos init + img_proj (32 lanes per row, coalesced float4) ----
  float pos0 = obs_pos[(wg0 + grow) * (L_OBS * 2) + (L_OBS - 1) * 2];
  float pos1 = obs_pos[(wg0 + grow) * (L_OBS * 2) + (L_OBS - 1) * 2 + 1];
  float ip0 = 0.f, ip1 = 0.f;
  {
    const float* irow = img + (long)(wg0 + grow) * C_DIM;
#pragma unroll 4
    for (int i = 0; i < 16; ++i) {
      const int k0 = i * 128 + c2 * 4;
      const f32x4 v  = *(const f32x4*)(irow + k0);
      const f32x4 wa = *(const f32x4*)(W_pred + (H_DIM + k0) * 2);
      const f32x4 wb = *(const f32x4*)(W_pred + (H_DIM + k0) * 2 + 4);
      ip0 = fmaf(v.x, wa.x, fmaf(v.y, wa.z, fmaf(v.z, wb.x, fmaf(v.w, wb.z, ip0))));
      ip1 = fmaf(v.x, wa.y, fmaf(v.y, wa.w, fmaf(v.z, wb.y, fmaf(v.w, wb.w, ip1))));
    }
#pragma unroll
    for (int m = 16; m >= 1; m >>= 1) { ip0 += __shfl_xor(ip0, m); ip1 += __shfl_xor(ip1, m); }
    ip0 += b_pred[0]; ip1 += b_pred[1];
  }
  __syncthreads();  // A_lds[0] ready

  int cur = 0;

  // exchange + gates + h-write. acc[rt][T] = gate (T*2+hi) of myu, rows rt*16+rq*4+q (no bias).
  auto gates_and_h = [&](f32x4 (&acc)[2][2], int nxt_, int s_, bool domask) {
    // send acc[1-hi][T], receive partner's -> rx[T] = the 2 gate-vectors this lane lacks for rt=hi
    f32x4 rx[2];
#pragma unroll
    for (int T = 0; T < 2; ++T)
#pragma unroll
      for (int q = 0; q < 4; ++q) {
        const float src = hi ? acc[0][T][q] : acc[1][T][q];
        rx[T][q] = __shfl_xor(src, 8);
      }
#pragma unroll
    for (int q = 0; q < 4; ++q) {
      const float iv = hi ? rx[0][q]     : acc[0][0][q];
      const float fv = hi ? acc[1][0][q] : rx[0][q];
      const float gv = hi ? rx[1][q]     : acc[0][1][q];
      const float ov = hi ? acc[1][1][q] : rx[1][q];
      const float A_ = ex2(fmaf(iv, -K1, nbi));
      const float F_ = ex2(fmaf(fv, -K1, nbf));
      const float B_ = ex2(fmaf(gv, -K2, nbg));
      const float C_ = ex2(fmaf(ov, -K1, nbo));
      const float P2 = 1.f + B_;
      const float PB = (1.f + A_) * P2;
      const float Q  = 1.f + F_;
      const float cn = fmaf(cs[q], PB, (2.f - P2) * Q) * rcpn(PB * Q);
      const float cc = fmaxf(fminf(cn, 40.f), -40.f);
      const float D_ = ex2(-K2 * cc);
      const float hn = (1.f - D_) * rcpn((1.f + D_) * (1.f + C_)); // tanh(cn)*sigmoid(o)
      bool act = true;
      if (domask) act = s_ >= ((sact >> (8 * q)) & 255);
      if (act) { cs[q] = cn; hreg[q] = hn; }
    }
    const unsigned int p01 = cvtpk(hreg[0], hreg[1]);
    const unsigned int p23 = cvtpk(hreg[2], hreg[3]);
    const int rowb = hi * 16 + rq * 4;
    A_lds[nxt_][rowb + 0][64 + myu] = (unsigned short)p01;
    A_lds[nxt_][rowb + 1][64 + myu] = (unsigned short)(p01 >> 16);
    A_lds[nxt_][rowb + 2][64 + myu] = (unsigned short)p23;
    A_lds[nxt_][rowb + 3][64 + myu] = (unsigned short)(p23 >> 16);
  };

  // ================= obs phase: steps s_min..18 =================
#pragma unroll 1
  for (int s = s_min; s < L_OBS - 1; ++s) {
    const int nxt = cur ^ 1;
    const int sN = (s + 2 <= L_OBS - 1) ? (s + 2) : (L_OBS - 1);
    const f32x2 rrN = *(const f32x2*)(relrow + sN * 2);

    f32x4 acc[2][2];
#pragma unroll
    for (int rt = 0; rt < 2; ++rt)
#pragma unroll
      for (int T = 0; T < 2; ++T) { acc[rt][T].x = 0.f; acc[rt][T].y = 0.f; acc[rt][T].z = 0.f; acc[rt][T].w = 0.f; }
#pragma unroll
    for (int rt = 0; rt < 2; ++rt)
#pragma unroll
      for (int ks = 0; ks < 6; ++ks) {
        const bf16x8 a = *(const bf16x8*)&A_lds[cur][rt * 16 + u15][ks * 32 + rq * 8];
#pragma unroll
        for (int T = 0; T < 2; ++T)
          acc[rt][T] = __builtin_amdgcn_mfma_f32_16x16x32_bf16(a, B[T][ks], acc[rt][T], 0, 0, 0);
      }

    // next-step e into A[nxt] (fills MFMA shadow)
    {
      const int j = c2 * 2;
      const float e0 = fmaxf(fmaf(rrN.x, We_lds[0][j],     fmaf(rrN.y, We_lds[1][j],     be_lds[j])),     0.f);
      const float e1 = fmaxf(fmaf(rrN.x, We_lds[0][j + 1], fmaf(rrN.y, We_lds[1][j + 1], be_lds[j + 1])), 0.f);
      *(unsigned int*)&A_lds[nxt][grow][j] = cvtpk(e0, e1);
    }

    gates_and_h(acc, nxt, s, true);
    cur = nxt;
    __syncthreads();
  }

  // ================= pred phase: 30 steps =================
#pragma unroll 1
  for (int p = 0; p < P_PRED; ++p) {
    const bool last = (p == P_PRED - 1);

    // rel chain: hv read + per-lane partial dot (4 units)
    const s16x4 hv = *(const s16x4*)&A_lds[cur][grow][64 + c2 * 4];
    float s0 = 0.f, s1 = 0.f;
#pragma unroll
    for (int i = 0; i < 4; ++i) {
      const float hfv = bf2f((unsigned short)hv[i]);
      s0 = fmaf(hfv, Wp_lds[c2 * 4 + i][0], s0);
      s1 = fmaf(hfv, Wp_lds[c2 * 4 + i][1], s1);
    }

    // h-part MFMAs (ks 2..5); overlap the shuffle tree
    f32x4 acc[2][2];
#pragma unroll
    for (int rt = 0; rt < 2; ++rt)
#pragma unroll
      for (int T = 0; T < 2; ++T) { acc[rt][T].x = 0.f; acc[rt][T].y = 0.f; acc[rt][T].z = 0.f; acc[rt][T].w = 0.f; }
    if (!last) {
#pragma unroll
      for (int rt = 0; rt < 2; ++rt)
#pragma unroll
        for (int ks4 = 0; ks4 < 4; ++ks4) {
          const bf16x8 a = *(const bf16x8*)&A_lds[cur][rt * 16 + u15][64 + ks4 * 32 + rq * 8];
#pragma unroll
          for (int T = 0; T < 2; ++T)
            acc[rt][T] = __builtin_amdgcn_mfma_f32_16x16x32_bf16(a, B[T][ks4 + 2], acc[rt][T], 0, 0, 0);
        }
    }

    // finish rel reduction (within 32-lane row group)
#pragma unroll
    for (int m = 16; m >= 1; m >>= 1) { s0 += __shfl_xor(s0, m); s1 += __shfl_xor(s1, m); }
    const float rel0 = s0 + ip0, rel1 = s1 + ip1;
    pos0 += rel0; pos1 += rel1;
    if (c2 == 0) {
      float2 o; o.x = pos0; o.y = pos1;
      *(float2*)&out[((long)(wg0 + grow) * P_PRED + p) * 2] = o;
    }
    if (last) break;

    // e = relu(rel @ W_embed + b_embed) into A[cur] cols 0..63
    {
      const int j = c2 * 2;
      const float e0 = fmaxf(fmaf(rel0, We_lds[0][j],     fmaf(rel1, We_lds[1][j],     be_lds[j])),     0.f);
      const float e1 = fmaxf(fmaf(rel0, We_lds[0][j + 1], fmaf(rel1, We_lds[1][j + 1], be_lds[j + 1])), 0.f);
      *(unsigned int*)&A_lds[cur][grow][j] = cvtpk(e0, e1);
    }
    __syncthreads();  // barrier B: e visible

    // e-part MFMAs (ks 0..1)
#pragma unroll
    for (int rt = 0; rt < 2; ++rt)
#pragma unroll
      for (int ks = 0; ks < 2; ++ks) {
        const bf16x8 a = *(const bf16x8*)&A_lds[cur][rt * 16 + u15][ks * 32 + rq * 8];
#pragma unroll
        for (int T = 0; T < 2; ++T)
          acc[rt][T] = __builtin_amdgcn_mfma_f32_16x16x32_bf16(a, B[T][ks], acc[rt][T], 0, 0, 0);
      }

    const int nxt = cur ^ 1;
    gates_and_h(acc, nxt, 0, false);
    cur = nxt;
    __syncthreads();  // barrier A: h visible
  }
}

extern "C" void kernel_launch(void* const* d_in, const int* in_sizes, int n_in,
                              void* d_out, int out_size, void* d_ws, size_t ws_size,
                              hipStream_t stream) {
  (void)in_sizes; (void)n_in; (void)out_size; (void)d_ws; (void)ws_size;
  lstm_traj<<<dim3(N_TOT / M_ROWS), dim3(NTH), 0, stream>>>(
      (const float*)d_in[0],  // img_embedding
      (const float*)d_in[1],  // obs_pos
      (const float*)d_in[2],  // obs_pos_rel
      (const int*)  d_in[3],  // obs_hist_size
      (const float*)d_in[4],  // h0
      (const float*)d_in[5],  // W_embed
      (const float*)d_in[6],  // b_embed
      (const float*)d_in[7],  // W_ih
      (const float*)d_in[8],  // W_hh
      (const float*)d_in[9],  // b_ih
      (const float*)d_in[10], // b_hh
      (const float*)d_in[11], // W_pred
      (const float*)d_in[12], // b_pred
      (float*)d_out);
}